// Round 1
// baseline (3245.746 us; speedup 1.0000x reference)
//
#include <hip/hip_runtime.h>

// EvolveGCN — key insight: scan discards h2 each step, so only the GRU weight
// evolution is sequential; graph conv runs once on feats[7].
// Pipeline:
//   deg/norm  -> GRU evolve (8 steps, column-parallel) -> W2m = W2@mlp_w1
//   Sx = S@feats[7] (edge scatter) -> H1 = rrelu(Sx@W1)
//   A  = S@H1 (edge scatter)       -> out = relu(A@W2m + b1)@w2 + b2

#define FF 128
#define HH 128
#define HM1 127
#define CC 64

static constexpr float RRELU_SLOPE = (1.0f / 8.0f + 1.0f / 3.0f) * 0.5f;

__device__ __forceinline__ float sigmoidf_(float x) {
    return 1.0f / (1.0f + expf(-x));
}

// ---------------------------------------------------------------------------
// GRU evolution: 8 sequential mat-GRU steps for both cells, column-parallel.
// Column j of W_new depends only on column j of W_old, so each block owns 4
// columns in LDS and loops all 8 steps with only block-level barriers.
// grid: 64 blocks (32 for cell1's 128 cols, 32 for cell2's 127 cols), 128 thr.
// ---------------------------------------------------------------------------
__global__ __launch_bounds__(128) void gru_evolve(
    const float* __restrict__ W1_0, const float* __restrict__ W2_0,
    const float* __restrict__ g1W, const float* __restrict__ g1U,
    const float* __restrict__ g1b, const float* __restrict__ g2W,
    const float* __restrict__ g2U, const float* __restrict__ g2b,
    float* __restrict__ W1f, float* __restrict__ W2f)
{
    const int i = threadIdx.x;            // row 0..127
    const int cb = blockIdx.x;            // 0..63
    const int cell = cb >> 5;             // 0: cell1, 1: cell2
    const int col0 = (cb & 31) * 4;

    const float* gW  = cell ? g2W : g1W;
    const float* gU  = cell ? g2U : g1U;
    const float* gb  = cell ? g2b : g1b;
    const int    ldb = cell ? HM1 : HH;   // bias col count
    const float* W0  = cell ? W2_0 : W1_0;
    const int   ldw0 = cell ? HM1 : HH;
    const int   ncol = cell ? HM1 : HH;

    __shared__ float w[4][128];
    __shared__ float rw[4][128];

    #pragma unroll
    for (int c = 0; c < 4; ++c) {
        int col = col0 + c;
        w[c][i] = (col < ncol) ? W0[i * ldw0 + col] : 0.0f;
    }
    __syncthreads();

    for (int s = 0; s < 8; ++s) {
        float zacc[4], racc[4];
        #pragma unroll
        for (int c = 0; c < 4; ++c) {
            int col = col0 + c;
            zacc[c] = (col < ncol) ? gb[0 * 128 * ldb + i * ldb + col] : 0.0f;
            racc[c] = (col < ncol) ? gb[1 * 128 * ldb + i * ldb + col] : 0.0f;
        }
        const float* w0r = gW + i * 128;
        const float* u0r = gU + i * 128;
        const float* w1r = gW + 128 * 128 + i * 128;
        const float* u1r = gU + 128 * 128 + i * 128;
        for (int k = 0; k < 128; ++k) {
            float a0 = w0r[k] + u0r[k];
            float a1 = w1r[k] + u1r[k];
            #pragma unroll
            for (int c = 0; c < 4; ++c) {
                float wk = w[c][k];
                zacc[c] += a0 * wk;
                racc[c] += a1 * wk;
            }
        }
        float z[4];
        #pragma unroll
        for (int c = 0; c < 4; ++c) {
            z[c] = sigmoidf_(zacc[c]);
            float r = sigmoidf_(racc[c]);
            rw[c][i] = r * w[c][i];
        }
        __syncthreads();

        float tacc[4];
        #pragma unroll
        for (int c = 0; c < 4; ++c) {
            int col = col0 + c;
            tacc[c] = (col < ncol) ? gb[2 * 128 * ldb + i * ldb + col] : 0.0f;
        }
        const float* w2r = gW + 2 * 128 * 128 + i * 128;
        const float* u2r = gU + 2 * 128 * 128 + i * 128;
        for (int k = 0; k < 128; ++k) {
            float b0 = w2r[k], b1 = u2r[k];
            #pragma unroll
            for (int c = 0; c < 4; ++c)
                tacc[c] += b0 * w[c][k] + b1 * rw[c][k];
        }
        __syncthreads();   // all reads of w done before overwrite

        #pragma unroll
        for (int c = 0; c < 4; ++c) {
            float t  = tanhf(tacc[c]);
            float nw = (1.0f - z[c]) * w[c][i] + z[c] * t;
            w[c][i] = nw;
        }
        __syncthreads();
    }

    float* Wf = cell ? W2f : W1f;
    #pragma unroll
    for (int c = 0; c < 4; ++c) {
        int col = col0 + c;
        if (col < ncol) Wf[i * 128 + col] = w[c][i];  // ld=128 (W2f padded)
    }
}

// W2m = W2 @ mlp_w1 : [128,127] @ [127,64] -> [128,64]
__global__ __launch_bounds__(256) void small_matmul(
    const float* __restrict__ W2f, const float* __restrict__ mw1,
    float* __restrict__ W2m)
{
    int idx = blockIdx.x * 256 + threadIdx.x;  // 8192 outputs
    int i = idx >> 6, j = idx & 63;
    float acc = 0.0f;
    for (int k = 0; k < HM1; ++k)
        acc += W2f[i * 128 + k] * mw1[k * 64 + j];
    W2m[idx] = acc;
}

__global__ __launch_bounds__(256) void deg_count(
    const int* __restrict__ src, const int* __restrict__ dst,
    int* __restrict__ degO, int* __restrict__ degI, int E)
{
    int e = blockIdx.x * 256 + threadIdx.x;
    if (e < E) {
        atomicAdd(&degO[src[e]], 1);
        atomicAdd(&degI[dst[e]], 1);
    }
}

__global__ __launch_bounds__(256) void norm_kernel(
    const int* __restrict__ src, const int* __restrict__ dst,
    const int* __restrict__ degO, const int* __restrict__ degI,
    float* __restrict__ normv, int E)
{
    int e = blockIdx.x * 256 + threadIdx.x;
    if (e < E) {
        float doo = fmaxf((float)degO[src[e]], 1.0f);
        float dii = fmaxf((float)degI[dst[e]], 1.0f);
        normv[e] = rsqrtf(doo) * rsqrtf(dii);
    }
}

// out[dst[e]] += x[src[e]] * norm[e]  (128 cols, 32 threads/edge, float4)
__global__ __launch_bounds__(256) void agg_scatter(
    const float* __restrict__ x, const int* __restrict__ src,
    const int* __restrict__ dst, const float* __restrict__ normv,
    float* __restrict__ out, int E)
{
    int t = blockIdx.x * 256 + threadIdx.x;
    int e = t >> 5;
    if (e >= E) return;
    int g = (t & 31) << 2;
    float n = normv[e];
    const float4 v = *reinterpret_cast<const float4*>(x + (size_t)src[e] * 128 + g);
    float* o = out + (size_t)dst[e] * 128 + g;
    unsafeAtomicAdd(o + 0, v.x * n);
    unsafeAtomicAdd(o + 1, v.y * n);
    unsafeAtomicAdd(o + 2, v.z * n);
    unsafeAtomicAdd(o + 3, v.w * n);
}

// Y = rrelu(X @ W) : X [N,128], W [128,128]. Thread-per-row, 64-col half per
// blockIdx.y (uniform -> W reads become scalar loads).
__global__ __launch_bounds__(256) void gemm_rrelu(
    const float* __restrict__ X, const float* __restrict__ W,
    float* __restrict__ Y, int N)
{
    int row = blockIdx.x * 256 + threadIdx.x;
    int c0 = blockIdx.y * 64;
    if (row >= N) return;

    float acc[64];
    #pragma unroll
    for (int j = 0; j < 64; ++j) acc[j] = 0.0f;

    const float4* xr = reinterpret_cast<const float4*>(X + (size_t)row * 128);
    for (int k4 = 0; k4 < 32; ++k4) {
        float4 xv = xr[k4];
        const float* wr = W + (k4 * 4) * 128 + c0;
        #pragma unroll
        for (int j = 0; j < 64; ++j) acc[j] += xv.x * wr[j];
        wr += 128;
        #pragma unroll
        for (int j = 0; j < 64; ++j) acc[j] += xv.y * wr[j];
        wr += 128;
        #pragma unroll
        for (int j = 0; j < 64; ++j) acc[j] += xv.z * wr[j];
        wr += 128;
        #pragma unroll
        for (int j = 0; j < 64; ++j) acc[j] += xv.w * wr[j];
    }

    float* yr = Y + (size_t)row * 128 + c0;
    #pragma unroll
    for (int j = 0; j < 64; j += 4) {
        float4 v;
        v.x = acc[j + 0] >= 0.0f ? acc[j + 0] : RRELU_SLOPE * acc[j + 0];
        v.y = acc[j + 1] >= 0.0f ? acc[j + 1] : RRELU_SLOPE * acc[j + 1];
        v.z = acc[j + 2] >= 0.0f ? acc[j + 2] : RRELU_SLOPE * acc[j + 2];
        v.w = acc[j + 3] >= 0.0f ? acc[j + 3] : RRELU_SLOPE * acc[j + 3];
        *reinterpret_cast<float4*>(yr + j) = v;
    }
}

// out = relu(A @ W2m + b1) @ w2 + b2 : A [N,128], W2m [128,64], w2 [64,2]
__global__ __launch_bounds__(256) void mlp_kernel(
    const float* __restrict__ A, const float* __restrict__ W2m,
    const float* __restrict__ b1, const float* __restrict__ w2,
    const float* __restrict__ b2, float* __restrict__ out, int N)
{
    int row = blockIdx.x * 256 + threadIdx.x;
    if (row >= N) return;

    float acc[64];
    #pragma unroll
    for (int j = 0; j < 64; ++j) acc[j] = 0.0f;

    const float4* ar = reinterpret_cast<const float4*>(A + (size_t)row * 128);
    for (int k4 = 0; k4 < 32; ++k4) {
        float4 xv = ar[k4];
        const float* wr = W2m + (k4 * 4) * 64;
        #pragma unroll
        for (int j = 0; j < 64; ++j) acc[j] += xv.x * wr[j];
        wr += 64;
        #pragma unroll
        for (int j = 0; j < 64; ++j) acc[j] += xv.y * wr[j];
        wr += 64;
        #pragma unroll
        for (int j = 0; j < 64; ++j) acc[j] += xv.z * wr[j];
        wr += 64;
        #pragma unroll
        for (int j = 0; j < 64; ++j) acc[j] += xv.w * wr[j];
    }

    float o0 = b2[0], o1 = b2[1];
    #pragma unroll
    for (int j = 0; j < 64; ++j) {
        float t = fmaxf(acc[j] + b1[j], 0.0f);
        o0 += t * w2[j * 2 + 0];
        o1 += t * w2[j * 2 + 1];
    }
    out[(size_t)row * 2 + 0] = o0;
    out[(size_t)row * 2 + 1] = o1;
}

extern "C" void kernel_launch(void* const* d_in, const int* in_sizes, int n_in,
                              void* d_out, int out_size, void* d_ws, size_t ws_size,
                              hipStream_t stream) {
    const float* feats = (const float*)d_in[0];
    const int*   src   = (const int*)d_in[1];
    const int*   dst   = (const int*)d_in[2];
    const float* W1_0  = (const float*)d_in[3];
    const float* W2_0  = (const float*)d_in[4];
    const float* g1W   = (const float*)d_in[5];
    const float* g1U   = (const float*)d_in[6];
    const float* g1b   = (const float*)d_in[7];
    const float* g2W   = (const float*)d_in[8];
    const float* g2U   = (const float*)d_in[9];
    const float* g2b   = (const float*)d_in[10];
    const float* mw1   = (const float*)d_in[11];
    const float* mb1   = (const float*)d_in[12];
    const float* mw2   = (const float*)d_in[13];
    const float* mb2   = (const float*)d_in[14];
    float* out = (float*)d_out;

    const int E = in_sizes[1];
    const int N = in_sizes[0] / (8 * 128);

    // workspace layout (floats)
    float* ws    = (float*)d_ws;
    float* W1f   = ws;                 // 128*128
    float* W2f   = ws + 16384;         // 128*128 (padded)
    float* W2m   = ws + 32768;         // 128*64
    int*   degO  = (int*)(ws + 40960); // N
    int*   degI  = degO + N;           // N
    float* normv = (float*)(degI + N); // E
    float* BUF1  = normv + E;          // N*128  (Sx, then A)
    float* H1    = BUF1 + (size_t)N * 128;  // N*128

    // degrees + norm
    hipMemsetAsync(degO, 0, sizeof(int) * 2 * (size_t)N, stream);
    deg_count<<<(E + 255) / 256, 256, 0, stream>>>(src, dst, degO, degI, E);
    norm_kernel<<<(E + 255) / 256, 256, 0, stream>>>(src, dst, degO, degI, normv, E);

    // weight evolution (independent of the above)
    gru_evolve<<<64, 128, 0, stream>>>(W1_0, W2_0, g1W, g1U, g1b, g2W, g2U, g2b, W1f, W2f);
    small_matmul<<<32, 256, 0, stream>>>(W2f, mw1, W2m);

    // Sx = S @ feats[7]
    hipMemsetAsync(BUF1, 0, sizeof(float) * (size_t)N * 128, stream);
    const float* x7 = feats + (size_t)7 * N * 128;
    agg_scatter<<<((size_t)E * 32 + 255) / 256, 256, 0, stream>>>(x7, src, dst, normv, BUF1, E);

    // H1 = rrelu(Sx @ W1)
    dim3 gg((N + 255) / 256, 2);
    gemm_rrelu<<<gg, 256, 0, stream>>>(BUF1, W1f, H1, N);

    // A = S @ H1
    hipMemsetAsync(BUF1, 0, sizeof(float) * (size_t)N * 128, stream);
    agg_scatter<<<((size_t)E * 32 + 255) / 256, 256, 0, stream>>>(H1, src, dst, normv, BUF1, E);

    // out = relu(A @ W2m + b1) @ w2 + b2
    mlp_kernel<<<(N + 255) / 256, 256, 0, stream>>>(BUF1, W2m, mb1, mw2, mb2, out, N);
}

// Round 2
// 834.045 us; speedup vs baseline: 3.8916x; 3.8916x over previous
//
#include <hip/hip_runtime.h>

// EvolveGCN — scan discards h2 each step, so only the GRU weight evolution is
// sequential; graph conv runs once on feats[7].
// Round 2: scatter-atomics -> CSR gather. Pipeline:
//   deg hist -> scan -> CSR build (counting sort by dst)
//   GRU evolve (8 steps, column-parallel) -> W2m = W2@mlp_w1
//   Sx = S@feats[7] (gather128) -> H1 = rrelu(Sx@W1) -> Y = H1@W2m
//   out = relu((S@Y) + b1)@w2 + b2  (gather64 + fused MLP head)

#define HM1 127

static constexpr float RRELU_SLOPE = (1.0f / 8.0f + 1.0f / 3.0f) * 0.5f;

__device__ __forceinline__ float sigmoidf_(float x) {
    return 1.0f / (1.0f + expf(-x));
}

// ---------------------------------------------------------------------------
// GRU evolution: 8 sequential mat-GRU steps for both cells, column-parallel.
// ---------------------------------------------------------------------------
__global__ __launch_bounds__(128) void gru_evolve(
    const float* __restrict__ W1_0, const float* __restrict__ W2_0,
    const float* __restrict__ g1W, const float* __restrict__ g1U,
    const float* __restrict__ g1b, const float* __restrict__ g2W,
    const float* __restrict__ g2U, const float* __restrict__ g2b,
    float* __restrict__ W1f, float* __restrict__ W2f)
{
    const int i = threadIdx.x;            // row 0..127
    const int cb = blockIdx.x;            // 0..63
    const int cell = cb >> 5;             // 0: cell1, 1: cell2
    const int col0 = (cb & 31) * 4;

    const float* gW  = cell ? g2W : g1W;
    const float* gU  = cell ? g2U : g1U;
    const float* gb  = cell ? g2b : g1b;
    const int    ldb = cell ? HM1 : 128;
    const float* W0  = cell ? W2_0 : W1_0;
    const int   ldw0 = cell ? HM1 : 128;
    const int   ncol = cell ? HM1 : 128;

    __shared__ float w[4][128];
    __shared__ float rw[4][128];

    #pragma unroll
    for (int c = 0; c < 4; ++c) {
        int col = col0 + c;
        w[c][i] = (col < ncol) ? W0[i * ldw0 + col] : 0.0f;
    }
    __syncthreads();

    for (int s = 0; s < 8; ++s) {
        float zacc[4], racc[4];
        #pragma unroll
        for (int c = 0; c < 4; ++c) {
            int col = col0 + c;
            zacc[c] = (col < ncol) ? gb[0 * 128 * ldb + i * ldb + col] : 0.0f;
            racc[c] = (col < ncol) ? gb[1 * 128 * ldb + i * ldb + col] : 0.0f;
        }
        const float* w0r = gW + i * 128;
        const float* u0r = gU + i * 128;
        const float* w1r = gW + 128 * 128 + i * 128;
        const float* u1r = gU + 128 * 128 + i * 128;
        for (int k = 0; k < 128; ++k) {
            float a0 = w0r[k] + u0r[k];
            float a1 = w1r[k] + u1r[k];
            #pragma unroll
            for (int c = 0; c < 4; ++c) {
                float wk = w[c][k];
                zacc[c] += a0 * wk;
                racc[c] += a1 * wk;
            }
        }
        float z[4];
        #pragma unroll
        for (int c = 0; c < 4; ++c) {
            z[c] = sigmoidf_(zacc[c]);
            float r = sigmoidf_(racc[c]);
            rw[c][i] = r * w[c][i];
        }
        __syncthreads();

        float tacc[4];
        #pragma unroll
        for (int c = 0; c < 4; ++c) {
            int col = col0 + c;
            tacc[c] = (col < ncol) ? gb[2 * 128 * ldb + i * ldb + col] : 0.0f;
        }
        const float* w2r = gW + 2 * 128 * 128 + i * 128;
        const float* u2r = gU + 2 * 128 * 128 + i * 128;
        for (int k = 0; k < 128; ++k) {
            float b0 = w2r[k], b1 = u2r[k];
            #pragma unroll
            for (int c = 0; c < 4; ++c)
                tacc[c] += b0 * w[c][k] + b1 * rw[c][k];
        }
        __syncthreads();

        #pragma unroll
        for (int c = 0; c < 4; ++c) {
            float t  = tanhf(tacc[c]);
            float nw = (1.0f - z[c]) * w[c][i] + z[c] * t;
            w[c][i] = nw;
        }
        __syncthreads();
    }

    float* Wf = cell ? W2f : W1f;
    #pragma unroll
    for (int c = 0; c < 4; ++c) {
        int col = col0 + c;
        if (col < ncol) Wf[i * 128 + col] = w[c][i];  // ld=128 (W2f padded)
    }
}

// W2m = W2 @ mlp_w1 : [128,127] @ [127,64] -> [128,64]
__global__ __launch_bounds__(256) void small_matmul(
    const float* __restrict__ W2f, const float* __restrict__ mw1,
    float* __restrict__ W2m)
{
    int idx = blockIdx.x * 256 + threadIdx.x;
    int i = idx >> 6, j = idx & 63;
    float acc = 0.0f;
    for (int k = 0; k < HM1; ++k)
        acc += W2f[i * 128 + k] * mw1[k * 64 + j];
    W2m[idx] = acc;
}

__global__ __launch_bounds__(256) void deg_count(
    const int* __restrict__ src, const int* __restrict__ dst,
    int* __restrict__ degO, int* __restrict__ degI, int E)
{
    int e = blockIdx.x * 256 + threadIdx.x;
    if (e < E) {
        atomicAdd(&degO[src[e]], 1);
        atomicAdd(&degI[dst[e]], 1);
    }
}

__global__ __launch_bounds__(256) void rdeg_kernel(
    const int* __restrict__ degO, const int* __restrict__ degI,
    float* __restrict__ rdegO, float* __restrict__ rdegI, int N)
{
    int n = blockIdx.x * 256 + threadIdx.x;
    if (n < N) {
        rdegO[n] = rsqrtf(fmaxf((float)degO[n], 1.0f));
        rdegI[n] = rsqrtf(fmaxf((float)degI[n], 1.0f));
    }
}

// Exclusive scan of degI -> row_ptr[0..N], single block of 1024 threads.
__global__ __launch_bounds__(1024) void scan_kernel(
    const int* __restrict__ degI, int* __restrict__ row_ptr, int N)
{
    __shared__ int sums[1024];
    const int t = threadIdx.x;
    const int chunk = (N + 1023) / 1024;
    const int lo = t * chunk;
    const int hi = min(lo + chunk, N);
    int s = 0;
    for (int i = lo; i < hi; ++i) s += degI[i];
    sums[t] = s;
    __syncthreads();
    // Hillis-Steele inclusive scan
    for (int off = 1; off < 1024; off <<= 1) {
        int v = (t >= off) ? sums[t - off] : 0;
        __syncthreads();
        sums[t] += v;
        __syncthreads();
    }
    int base = (t > 0) ? sums[t - 1] : 0;
    for (int i = lo; i < hi; ++i) {
        row_ptr[i] = base;
        base += degI[i];
    }
    if (t == 1023) row_ptr[N] = sums[1023];
}

// Counting-sort edge placement: srcs[] sorted by dst.
__global__ __launch_bounds__(256) void build_csr(
    const int* __restrict__ src, const int* __restrict__ dst,
    const int* __restrict__ row_ptr, int* __restrict__ cursor,
    int* __restrict__ srcs, int E)
{
    int e = blockIdx.x * 256 + threadIdx.x;
    if (e < E) {
        int d = dst[e];
        int pos = row_ptr[d] + atomicAdd(&cursor[d], 1);
        srcs[pos] = src[e];
    }
}

// Sx[n,:] = rdegI[n] * sum_{s in in(n)} rdegO[s] * x[s,:]   (128 cols)
// One wave per node; lane owns 2 cols (float2).
__global__ __launch_bounds__(256) void gather128(
    const float* __restrict__ x, const int* __restrict__ srcs,
    const int* __restrict__ row_ptr, const float* __restrict__ rdegO,
    const float* __restrict__ rdegI, float* __restrict__ out, int N)
{
    int n = (blockIdx.x * 256 + threadIdx.x) >> 6;
    int lane = threadIdx.x & 63;
    if (n >= N) return;
    int lo = row_ptr[n], hi = row_ptr[n + 1];
    float ax = 0.0f, ay = 0.0f;
    int p = lo;
    for (; p + 2 <= hi; p += 2) {
        int s0 = srcs[p], s1 = srcs[p + 1];
        float w0 = rdegO[s0], w1 = rdegO[s1];
        float2 v0 = *reinterpret_cast<const float2*>(x + (size_t)s0 * 128 + lane * 2);
        float2 v1 = *reinterpret_cast<const float2*>(x + (size_t)s1 * 128 + lane * 2);
        ax += w0 * v0.x + w1 * v1.x;
        ay += w0 * v0.y + w1 * v1.y;
    }
    if (p < hi) {
        int s0 = srcs[p];
        float w0 = rdegO[s0];
        float2 v0 = *reinterpret_cast<const float2*>(x + (size_t)s0 * 128 + lane * 2);
        ax += w0 * v0.x;
        ay += w0 * v0.y;
    }
    float ri = rdegI[n];
    float2 o; o.x = ax * ri; o.y = ay * ri;
    *reinterpret_cast<float2*>(out + (size_t)n * 128 + lane * 2) = o;
}

// H1 = rrelu(X @ W) : X [N,128], W [128,128]. Thread-per-row, 64-col half per
// blockIdx.y (W addresses thread-uniform -> scalar loads).
__global__ __launch_bounds__(256) void gemm_rrelu(
    const float* __restrict__ X, const float* __restrict__ W,
    float* __restrict__ Y, int N)
{
    int row = blockIdx.x * 256 + threadIdx.x;
    int c0 = blockIdx.y * 64;
    if (row >= N) return;

    float acc[64];
    #pragma unroll
    for (int j = 0; j < 64; ++j) acc[j] = 0.0f;

    const float4* xr = reinterpret_cast<const float4*>(X + (size_t)row * 128);
    for (int k4 = 0; k4 < 32; ++k4) {
        float4 xv = xr[k4];
        const float* wr = W + (k4 * 4) * 128 + c0;
        #pragma unroll
        for (int j = 0; j < 64; ++j) acc[j] += xv.x * wr[j];
        wr += 128;
        #pragma unroll
        for (int j = 0; j < 64; ++j) acc[j] += xv.y * wr[j];
        wr += 128;
        #pragma unroll
        for (int j = 0; j < 64; ++j) acc[j] += xv.z * wr[j];
        wr += 128;
        #pragma unroll
        for (int j = 0; j < 64; ++j) acc[j] += xv.w * wr[j];
    }

    float* yr = Y + (size_t)row * 128 + c0;
    #pragma unroll
    for (int j = 0; j < 64; j += 4) {
        float4 v;
        v.x = acc[j + 0] >= 0.0f ? acc[j + 0] : RRELU_SLOPE * acc[j + 0];
        v.y = acc[j + 1] >= 0.0f ? acc[j + 1] : RRELU_SLOPE * acc[j + 1];
        v.z = acc[j + 2] >= 0.0f ? acc[j + 2] : RRELU_SLOPE * acc[j + 2];
        v.w = acc[j + 3] >= 0.0f ? acc[j + 3] : RRELU_SLOPE * acc[j + 3];
        *reinterpret_cast<float4*>(yr + j) = v;
    }
}

// Y = H1 @ W2m : [N,128] @ [128,64]
__global__ __launch_bounds__(256) void gemm_y(
    const float* __restrict__ H1, const float* __restrict__ W2m,
    float* __restrict__ Y, int N)
{
    int row = blockIdx.x * 256 + threadIdx.x;
    if (row >= N) return;

    float acc[64];
    #pragma unroll
    for (int j = 0; j < 64; ++j) acc[j] = 0.0f;

    const float4* hr = reinterpret_cast<const float4*>(H1 + (size_t)row * 128);
    for (int k4 = 0; k4 < 32; ++k4) {
        float4 h = hr[k4];
        const float* wr = W2m + (k4 * 4) * 64;
        #pragma unroll
        for (int j = 0; j < 64; ++j) acc[j] += h.x * wr[j];
        wr += 64;
        #pragma unroll
        for (int j = 0; j < 64; ++j) acc[j] += h.y * wr[j];
        wr += 64;
        #pragma unroll
        for (int j = 0; j < 64; ++j) acc[j] += h.z * wr[j];
        wr += 64;
        #pragma unroll
        for (int j = 0; j < 64; ++j) acc[j] += h.w * wr[j];
    }

    float* yr = Y + (size_t)row * 64;
    #pragma unroll
    for (int j = 0; j < 64; j += 4) {
        float4 v; v.x = acc[j]; v.y = acc[j+1]; v.z = acc[j+2]; v.w = acc[j+3];
        *reinterpret_cast<float4*>(yr + j) = v;
    }
}

// Z[n,:] = rdegI[n] * sum rdegO[s]*Y[s,:] (64 cols, lane=col), then fused MLP:
// out[n,:] = relu(Z + b1) @ w2 + b2 via wave reduction.
__global__ __launch_bounds__(256) void gather64_mlp(
    const float* __restrict__ Y, const int* __restrict__ srcs,
    const int* __restrict__ row_ptr, const float* __restrict__ rdegO,
    const float* __restrict__ rdegI, const float* __restrict__ b1,
    const float* __restrict__ w2, const float* __restrict__ b2,
    float* __restrict__ out, int N)
{
    int n = (blockIdx.x * 256 + threadIdx.x) >> 6;
    int lane = threadIdx.x & 63;
    if (n >= N) return;
    int lo = row_ptr[n], hi = row_ptr[n + 1];
    float acc = 0.0f;
    int p = lo;
    for (; p + 2 <= hi; p += 2) {
        int s0 = srcs[p], s1 = srcs[p + 1];
        acc += rdegO[s0] * Y[(size_t)s0 * 64 + lane]
             + rdegO[s1] * Y[(size_t)s1 * 64 + lane];
    }
    if (p < hi) {
        int s0 = srcs[p];
        acc += rdegO[s0] * Y[(size_t)s0 * 64 + lane];
    }
    float z = acc * rdegI[n];
    float t = fmaxf(z + b1[lane], 0.0f);
    float p0 = t * w2[lane * 2 + 0];
    float p1 = t * w2[lane * 2 + 1];
    #pragma unroll
    for (int off = 32; off; off >>= 1) {
        p0 += __shfl_xor(p0, off);
        p1 += __shfl_xor(p1, off);
    }
    if (lane == 0) {
        out[(size_t)n * 2 + 0] = p0 + b2[0];
        out[(size_t)n * 2 + 1] = p1 + b2[1];
    }
}

extern "C" void kernel_launch(void* const* d_in, const int* in_sizes, int n_in,
                              void* d_out, int out_size, void* d_ws, size_t ws_size,
                              hipStream_t stream) {
    const float* feats = (const float*)d_in[0];
    const int*   src   = (const int*)d_in[1];
    const int*   dst   = (const int*)d_in[2];
    const float* W1_0  = (const float*)d_in[3];
    const float* W2_0  = (const float*)d_in[4];
    const float* g1W   = (const float*)d_in[5];
    const float* g1U   = (const float*)d_in[6];
    const float* g1b   = (const float*)d_in[7];
    const float* g2W   = (const float*)d_in[8];
    const float* g2U   = (const float*)d_in[9];
    const float* g2b   = (const float*)d_in[10];
    const float* mw1   = (const float*)d_in[11];
    const float* mb1   = (const float*)d_in[12];
    const float* mw2   = (const float*)d_in[13];
    const float* mb2   = (const float*)d_in[14];
    float* out = (float*)d_out;

    const int E = in_sizes[1];
    const int N = in_sizes[0] / (8 * 128);

    // workspace layout
    float* ws    = (float*)d_ws;
    float* W1f   = ws;                        // 16384
    float* W2f   = W1f + 16384;               // 16384
    float* W2m   = W2f + 16384;               // 8192
    float* rdegO = W2m + 8192;                // N
    float* rdegI = rdegO + N;                 // N
    int*   degO  = (int*)(rdegI + N);         // N  ┐
    int*   degI  = degO + N;                  // N  ├ contiguous, one memset
    int*   cursor= degI + N;                  // N  ┘
    int*   row_ptr = cursor + N;              // N+1
    int*   srcs  = row_ptr + N + 1;           // E
    float* Sx    = (float*)(srcs + E);        // N*128  (later reused as Y)
    float* H1    = Sx + (size_t)N * 128;      // N*128
    float* Yb    = Sx;                        // N*64 aliases Sx (dead by then)

    // ---- CSR build ----
    hipMemsetAsync(degO, 0, sizeof(int) * 3 * (size_t)N, stream);
    deg_count<<<(E + 255) / 256, 256, 0, stream>>>(src, dst, degO, degI, E);
    rdeg_kernel<<<(N + 255) / 256, 256, 0, stream>>>(degO, degI, rdegO, rdegI, N);
    scan_kernel<<<1, 1024, 0, stream>>>(degI, row_ptr, N);
    build_csr<<<(E + 255) / 256, 256, 0, stream>>>(src, dst, row_ptr, cursor, srcs, E);

    // ---- weight evolution (independent) ----
    gru_evolve<<<64, 128, 0, stream>>>(W1_0, W2_0, g1W, g1U, g1b, g2W, g2U, g2b, W1f, W2f);
    small_matmul<<<32, 256, 0, stream>>>(W2f, mw1, W2m);

    // ---- graph conv on feats[7] ----
    const float* x7 = feats + (size_t)7 * N * 128;
    int ngather = ((N * 64) + 255) / 256;     // 4 nodes (waves) per block
    gather128<<<ngather, 256, 0, stream>>>(x7, srcs, row_ptr, rdegO, rdegI, Sx, N);

    dim3 gg((N + 255) / 256, 2);
    gemm_rrelu<<<gg, 256, 0, stream>>>(Sx, W1f, H1, N);
    gemm_y<<<(N + 255) / 256, 256, 0, stream>>>(H1, W2m, Yb, N);

    gather64_mlp<<<ngather, 256, 0, stream>>>(Yb, srcs, row_ptr, rdegO, rdegI,
                                              mb1, mw2, mb2, out, N);
}

// Round 3
// 726.591 us; speedup vs baseline: 4.4671x; 1.1479x over previous
//
#include <hip/hip_runtime.h>

// EvolveGCN — scan discards h2 each step, so only the GRU weight evolution is
// sequential; graph conv runs once on feats[7].
// Round 3: (a) gru_evolve reads transposed gate mats (coalesced) with 1 col
// per block (255 blocks); (b) gathers use shfl-broadcast edge indices to break
// the srcs->row dependent-load chain; (c) gemm_y pre-scales rows by rdegO.

#define HM1 127

static constexpr float RRELU_SLOPE = (1.0f / 8.0f + 1.0f / 3.0f) * 0.5f;

__device__ __forceinline__ float sigmoidf_(float x) {
    return 1.0f / (1.0f + expf(-x));
}

// ---------------------------------------------------------------------------
// Transposed gate matrices:
//   AT[cell][0][k][i] = gW[0][i][k] + gU[0][i][k]   (z gate, W+U folded)
//   AT[cell][1][k][i] = gW[1][i][k] + gU[1][i][k]   (r gate)
//   AT[cell][2][k][i] = gW[2][i][k]                 (h~ W part)
//   AT[cell][3][k][i] = gU[2][i][k]                 (h~ U part)
// ---------------------------------------------------------------------------
__global__ __launch_bounds__(256) void prep_gates(
    const float* __restrict__ g1W, const float* __restrict__ g1U,
    const float* __restrict__ g2W, const float* __restrict__ g2U,
    float* __restrict__ AT)
{
    int t = blockIdx.x * 256 + threadIdx.x;   // < 8*16384
    int m = t >> 14;          // matrix 0..7
    int k = (t >> 7) & 127;   // row of AT
    int i = t & 127;          // col of AT
    const float* W = (m < 4) ? g1W : g2W;
    const float* U = (m < 4) ? g1U : g2U;
    int which = m & 3;
    float v;
    if (which == 0)      v = W[i * 128 + k] + U[i * 128 + k];
    else if (which == 1) v = W[16384 + i * 128 + k] + U[16384 + i * 128 + k];
    else if (which == 2) v = W[32768 + i * 128 + k];
    else                 v = U[32768 + i * 128 + k];
    AT[t] = v;
}

// ---------------------------------------------------------------------------
// GRU evolution: 8 sequential mat-GRU steps, one column per block.
// blocks 0..127: cell1 col; blocks 128..254: cell2 col. 128 threads = rows.
// ---------------------------------------------------------------------------
__global__ __launch_bounds__(128) void gru_evolve(
    const float* __restrict__ W1_0, const float* __restrict__ W2_0,
    const float* __restrict__ AT,
    const float* __restrict__ g1b, const float* __restrict__ g2b,
    float* __restrict__ W1f, float* __restrict__ W2f)
{
    const int i = threadIdx.x;                 // row
    const int bid = blockIdx.x;                // 0..254
    const int cell = (bid >= 128) ? 1 : 0;
    const int c = cell ? (bid - 128) : bid;

    const float* A  = AT + cell * 4 * 16384;
    const float* A0 = A;
    const float* A1 = A + 16384;
    const float* B0 = A + 32768;
    const float* B1 = A + 49152;
    const float* gb = cell ? g2b : g1b;
    const int   ldb = cell ? HM1 : 128;
    const float* W0 = cell ? W2_0 : W1_0;
    const int   ldw = cell ? HM1 : 128;

    __shared__ float w[128];
    __shared__ float rw[128];

    const float zb = gb[i * ldb + c];
    const float rb = gb[128 * ldb + i * ldb + c];
    const float hb = gb[2 * 128 * ldb + i * ldb + c];
    float wi = W0[i * ldw + c];
    w[i] = wi;
    __syncthreads();

    for (int s = 0; s < 8; ++s) {
        float zacc = zb, racc = rb, tacc = hb;
        #pragma unroll 4
        for (int k = 0; k < 128; ++k) {
            float wk = w[k];
            zacc += A0[k * 128 + i] * wk;
            racc += A1[k * 128 + i] * wk;
            tacc += B0[k * 128 + i] * wk;
        }
        float r = sigmoidf_(racc);
        rw[i] = r * wi;
        __syncthreads();
        #pragma unroll 4
        for (int k = 0; k < 128; ++k)
            tacc += B1[k * 128 + i] * rw[k];
        float z = sigmoidf_(zacc);
        float t = tanhf(tacc);
        float nwi = (1.0f - z) * wi + z * t;
        __syncthreads();          // all loop2 reads of rw done
        wi = nwi;
        w[i] = nwi;
        __syncthreads();          // w visible for next step
    }

    float* Wf = cell ? W2f : W1f;
    Wf[i * 128 + c] = wi;         // ld=128 (W2f padded)
}

// W2m = W2 @ mlp_w1 : [128,127] @ [127,64] -> [128,64]
__global__ __launch_bounds__(256) void small_matmul(
    const float* __restrict__ W2f, const float* __restrict__ mw1,
    float* __restrict__ W2m)
{
    int idx = blockIdx.x * 256 + threadIdx.x;
    int i = idx >> 6, j = idx & 63;
    float acc = 0.0f;
    for (int k = 0; k < HM1; ++k)
        acc += W2f[i * 128 + k] * mw1[k * 64 + j];
    W2m[idx] = acc;
}

__global__ __launch_bounds__(256) void deg_count(
    const int* __restrict__ src, const int* __restrict__ dst,
    int* __restrict__ degO, int* __restrict__ degI, int E)
{
    int e = blockIdx.x * 256 + threadIdx.x;
    if (e < E) {
        atomicAdd(&degO[src[e]], 1);
        atomicAdd(&degI[dst[e]], 1);
    }
}

__global__ __launch_bounds__(256) void rdeg_kernel(
    const int* __restrict__ degO, const int* __restrict__ degI,
    float* __restrict__ rdegO, float* __restrict__ rdegI, int N)
{
    int n = blockIdx.x * 256 + threadIdx.x;
    if (n < N) {
        rdegO[n] = rsqrtf(fmaxf((float)degO[n], 1.0f));
        rdegI[n] = rsqrtf(fmaxf((float)degI[n], 1.0f));
    }
}

// Exclusive scan of degI -> row_ptr[0..N], single block of 1024 threads.
__global__ __launch_bounds__(1024) void scan_kernel(
    const int* __restrict__ degI, int* __restrict__ row_ptr, int N)
{
    __shared__ int sums[1024];
    const int t = threadIdx.x;
    const int chunk = (N + 1023) / 1024;
    const int lo = t * chunk;
    const int hi = min(lo + chunk, N);
    int s = 0;
    for (int i = lo; i < hi; ++i) s += degI[i];
    sums[t] = s;
    __syncthreads();
    for (int off = 1; off < 1024; off <<= 1) {
        int v = (t >= off) ? sums[t - off] : 0;
        __syncthreads();
        sums[t] += v;
        __syncthreads();
    }
    int base = (t > 0) ? sums[t - 1] : 0;
    for (int i = lo; i < hi; ++i) {
        row_ptr[i] = base;
        base += degI[i];
    }
    if (t == 1023) row_ptr[N] = sums[1023];
}

// Counting-sort edge placement: srcs[] sorted by dst.
__global__ __launch_bounds__(256) void build_csr(
    const int* __restrict__ src, const int* __restrict__ dst,
    const int* __restrict__ row_ptr, int* __restrict__ cursor,
    int* __restrict__ srcs, int E)
{
    int e = blockIdx.x * 256 + threadIdx.x;
    if (e < E) {
        int d = dst[e];
        int pos = row_ptr[d] + atomicAdd(&cursor[d], 1);
        srcs[pos] = src[e];
    }
}

// Sx[n,:] = rdegI[n] * sum_{s in in(n)} rdegO[s] * x[s,:]   (128 cols)
// One wave per node; lane owns 2 cols. Edge indices loaded coalesced per
// 64-chunk, broadcast via shfl (uniform j -> readlane/SGPR row base).
__global__ __launch_bounds__(256) void gather128(
    const float* __restrict__ x, const int* __restrict__ srcs,
    const int* __restrict__ row_ptr, const float* __restrict__ rdegO,
    const float* __restrict__ rdegI, float* __restrict__ out, int N)
{
    int n = (blockIdx.x * 256 + threadIdx.x) >> 6;
    int lane = threadIdx.x & 63;
    if (n >= N) return;
    int lo = row_ptr[n], hi = row_ptr[n + 1];
    float ax = 0.0f, ay = 0.0f;
    for (int base = lo; base < hi; base += 64) {
        int cnt = min(hi - base, 64);
        int idx   = (lane < cnt) ? srcs[base + lane] : 0;
        float wgt = (lane < cnt) ? rdegO[idx] : 0.0f;
        int j = 0;
        for (; j + 4 <= cnt; j += 4) {
            int s0 = __shfl(idx, j + 0), s1 = __shfl(idx, j + 1);
            int s2 = __shfl(idx, j + 2), s3 = __shfl(idx, j + 3);
            float w0 = __shfl(wgt, j + 0), w1 = __shfl(wgt, j + 1);
            float w2 = __shfl(wgt, j + 2), w3 = __shfl(wgt, j + 3);
            float2 v0 = *reinterpret_cast<const float2*>(x + (size_t)s0 * 128 + lane * 2);
            float2 v1 = *reinterpret_cast<const float2*>(x + (size_t)s1 * 128 + lane * 2);
            float2 v2 = *reinterpret_cast<const float2*>(x + (size_t)s2 * 128 + lane * 2);
            float2 v3 = *reinterpret_cast<const float2*>(x + (size_t)s3 * 128 + lane * 2);
            ax += w0 * v0.x + w1 * v1.x + w2 * v2.x + w3 * v3.x;
            ay += w0 * v0.y + w1 * v1.y + w2 * v2.y + w3 * v3.y;
        }
        for (; j < cnt; ++j) {
            int s0 = __shfl(idx, j);
            float w0 = __shfl(wgt, j);
            float2 v0 = *reinterpret_cast<const float2*>(x + (size_t)s0 * 128 + lane * 2);
            ax += w0 * v0.x;
            ay += w0 * v0.y;
        }
    }
    float ri = rdegI[n];
    float2 o; o.x = ax * ri; o.y = ay * ri;
    *reinterpret_cast<float2*>(out + (size_t)n * 128 + lane * 2) = o;
}

// H1 = rrelu(X @ W) : X [N,128], W [128,128]. Thread-per-row, 64-col half per
// blockIdx.y (W addresses thread-uniform -> scalar loads).
__global__ __launch_bounds__(256) void gemm_rrelu(
    const float* __restrict__ X, const float* __restrict__ W,
    float* __restrict__ Y, int N)
{
    int row = blockIdx.x * 256 + threadIdx.x;
    int c0 = blockIdx.y * 64;
    if (row >= N) return;

    float acc[64];
    #pragma unroll
    for (int j = 0; j < 64; ++j) acc[j] = 0.0f;

    const float4* xr = reinterpret_cast<const float4*>(X + (size_t)row * 128);
    for (int k4 = 0; k4 < 32; ++k4) {
        float4 xv = xr[k4];
        const float* wr = W + (k4 * 4) * 128 + c0;
        #pragma unroll
        for (int j = 0; j < 64; ++j) acc[j] += xv.x * wr[j];
        wr += 128;
        #pragma unroll
        for (int j = 0; j < 64; ++j) acc[j] += xv.y * wr[j];
        wr += 128;
        #pragma unroll
        for (int j = 0; j < 64; ++j) acc[j] += xv.z * wr[j];
        wr += 128;
        #pragma unroll
        for (int j = 0; j < 64; ++j) acc[j] += xv.w * wr[j];
    }

    float* yr = Y + (size_t)row * 128 + c0;
    #pragma unroll
    for (int j = 0; j < 64; j += 4) {
        float4 v;
        v.x = acc[j + 0] >= 0.0f ? acc[j + 0] : RRELU_SLOPE * acc[j + 0];
        v.y = acc[j + 1] >= 0.0f ? acc[j + 1] : RRELU_SLOPE * acc[j + 1];
        v.z = acc[j + 2] >= 0.0f ? acc[j + 2] : RRELU_SLOPE * acc[j + 2];
        v.w = acc[j + 3] >= 0.0f ? acc[j + 3] : RRELU_SLOPE * acc[j + 3];
        *reinterpret_cast<float4*>(yr + j) = v;
    }
}

// Ys = diag(rdegO) * (H1 @ W2m) : [N,128] @ [128,64], rows pre-scaled so the
// second gather needs no per-edge weight.
__global__ __launch_bounds__(256) void gemm_y(
    const float* __restrict__ H1, const float* __restrict__ W2m,
    const float* __restrict__ rdegO, float* __restrict__ Ys, int N)
{
    int row = blockIdx.x * 256 + threadIdx.x;
    if (row >= N) return;

    float acc[64];
    #pragma unroll
    for (int j = 0; j < 64; ++j) acc[j] = 0.0f;

    const float4* hr = reinterpret_cast<const float4*>(H1 + (size_t)row * 128);
    for (int k4 = 0; k4 < 32; ++k4) {
        float4 h = hr[k4];
        const float* wr = W2m + (k4 * 4) * 64;
        #pragma unroll
        for (int j = 0; j < 64; ++j) acc[j] += h.x * wr[j];
        wr += 64;
        #pragma unroll
        for (int j = 0; j < 64; ++j) acc[j] += h.y * wr[j];
        wr += 64;
        #pragma unroll
        for (int j = 0; j < 64; ++j) acc[j] += h.z * wr[j];
        wr += 64;
        #pragma unroll
        for (int j = 0; j < 64; ++j) acc[j] += h.w * wr[j];
    }

    float ro = rdegO[row];
    float* yr = Ys + (size_t)row * 64;
    #pragma unroll
    for (int j = 0; j < 64; j += 4) {
        float4 v;
        v.x = acc[j] * ro; v.y = acc[j + 1] * ro;
        v.z = acc[j + 2] * ro; v.w = acc[j + 3] * ro;
        *reinterpret_cast<float4*>(yr + j) = v;
    }
}

// Z[n,:] = rdegI[n] * sum Ys[s,:] (64 cols, lane=col), then fused MLP head:
// out[n,:] = relu(Z + b1) @ w2 + b2 via wave reduction.
__global__ __launch_bounds__(256) void gather64_mlp(
    const float* __restrict__ Ys, const int* __restrict__ srcs,
    const int* __restrict__ row_ptr, const float* __restrict__ rdegI,
    const float* __restrict__ b1, const float* __restrict__ w2,
    const float* __restrict__ b2, float* __restrict__ out, int N)
{
    int n = (blockIdx.x * 256 + threadIdx.x) >> 6;
    int lane = threadIdx.x & 63;
    if (n >= N) return;
    int lo = row_ptr[n], hi = row_ptr[n + 1];
    float acc = 0.0f;
    for (int base = lo; base < hi; base += 64) {
        int cnt = min(hi - base, 64);
        int idx = (lane < cnt) ? srcs[base + lane] : 0;
        int j = 0;
        for (; j + 4 <= cnt; j += 4) {
            int s0 = __shfl(idx, j + 0), s1 = __shfl(idx, j + 1);
            int s2 = __shfl(idx, j + 2), s3 = __shfl(idx, j + 3);
            acc += Ys[(size_t)s0 * 64 + lane] + Ys[(size_t)s1 * 64 + lane]
                 + Ys[(size_t)s2 * 64 + lane] + Ys[(size_t)s3 * 64 + lane];
        }
        for (; j < cnt; ++j) {
            int s0 = __shfl(idx, j);
            acc += Ys[(size_t)s0 * 64 + lane];
        }
    }
    float z = acc * rdegI[n];
    float t = fmaxf(z + b1[lane], 0.0f);
    float p0 = t * w2[lane * 2 + 0];
    float p1 = t * w2[lane * 2 + 1];
    #pragma unroll
    for (int off = 32; off; off >>= 1) {
        p0 += __shfl_xor(p0, off);
        p1 += __shfl_xor(p1, off);
    }
    if (lane == 0) {
        out[(size_t)n * 2 + 0] = p0 + b2[0];
        out[(size_t)n * 2 + 1] = p1 + b2[1];
    }
}

extern "C" void kernel_launch(void* const* d_in, const int* in_sizes, int n_in,
                              void* d_out, int out_size, void* d_ws, size_t ws_size,
                              hipStream_t stream) {
    const float* feats = (const float*)d_in[0];
    const int*   src   = (const int*)d_in[1];
    const int*   dst   = (const int*)d_in[2];
    const float* W1_0  = (const float*)d_in[3];
    const float* W2_0  = (const float*)d_in[4];
    const float* g1W   = (const float*)d_in[5];
    const float* g1U   = (const float*)d_in[6];
    const float* g1b   = (const float*)d_in[7];
    const float* g2W   = (const float*)d_in[8];
    const float* g2U   = (const float*)d_in[9];
    const float* g2b   = (const float*)d_in[10];
    const float* mw1   = (const float*)d_in[11];
    const float* mb1   = (const float*)d_in[12];
    const float* mw2   = (const float*)d_in[13];
    const float* mb2   = (const float*)d_in[14];
    float* out = (float*)d_out;

    const int E = in_sizes[1];
    const int N = in_sizes[0] / (8 * 128);

    // workspace layout
    float* ws    = (float*)d_ws;
    float* W1f   = ws;                        // 16384
    float* W2f   = W1f + 16384;               // 16384
    float* W2m   = W2f + 16384;               // 8192
    float* AT    = W2m + 8192;                // 8*16384
    float* rdegO = AT + 8 * 16384;            // N
    float* rdegI = rdegO + N;                 // N
    int*   degO  = (int*)(rdegI + N);         // N  ┐
    int*   degI  = degO + N;                  // N  ├ contiguous, one memset
    int*   cursor= degI + N;                  // N  ┘
    int*   row_ptr = cursor + N;              // N+1
    int*   srcs  = row_ptr + N + 1;           // E
    float* Sx    = (float*)(srcs + E);        // N*128
    float* H1    = Sx + (size_t)N * 128;      // N*128
    float* Ys    = Sx;                        // N*64 aliases Sx (dead by then)

    // ---- CSR build ----
    hipMemsetAsync(degO, 0, sizeof(int) * 3 * (size_t)N, stream);
    deg_count<<<(E + 255) / 256, 256, 0, stream>>>(src, dst, degO, degI, E);
    rdeg_kernel<<<(N + 255) / 256, 256, 0, stream>>>(degO, degI, rdegO, rdegI, N);
    scan_kernel<<<1, 1024, 0, stream>>>(degI, row_ptr, N);
    build_csr<<<(E + 255) / 256, 256, 0, stream>>>(src, dst, row_ptr, cursor, srcs, E);

    // ---- weight evolution ----
    prep_gates<<<512, 256, 0, stream>>>(g1W, g1U, g2W, g2U, AT);
    gru_evolve<<<255, 128, 0, stream>>>(W1_0, W2_0, AT, g1b, g2b, W1f, W2f);
    small_matmul<<<32, 256, 0, stream>>>(W2f, mw1, W2m);

    // ---- graph conv on feats[7] ----
    const float* x7 = feats + (size_t)7 * N * 128;
    int ngather = ((N * 64) + 255) / 256;     // 4 nodes (waves) per block
    gather128<<<ngather, 256, 0, stream>>>(x7, srcs, row_ptr, rdegO, rdegI, Sx, N);

    dim3 gg((N + 255) / 256, 2);
    gemm_rrelu<<<gg, 256, 0, stream>>>(Sx, W1f, H1, N);
    gemm_y<<<(N + 255) / 256, 256, 0, stream>>>(H1, W2m, rdegO, Ys, N);

    gather64_mlp<<<ngather, 256, 0, stream>>>(Ys, srcs, row_ptr, rdegI,
                                              mb1, mw2, mb2, out, N);
}

// Round 4
// 635.698 us; speedup vs baseline: 5.1058x; 1.1430x over previous
//
#include <hip/hip_runtime.h>

// EvolveGCN — only the GRU weight evolution is sequential; graph conv runs
// once on feats[7]. Round 4: DAG-restructured into phases (independent work
// merged into one launch via blockIdx partition), gathers made weight-free by
// pre-scaling (Zs = rdegO ⊙ (x7@W1)), rrelu fused into gather epilogue.
//
// phase1: deg_count ∥ prep_gates
// phase2: gru_evolve (2 cols/block) ∥ scan(degI→row_ptr) ∥ rdeg
// phase3: build_csr ∥ gemm_z (Zs = rdegO⊙(x7@W1)) ∥ small_matmul (W2m=W2@mw1)
// gather128: H1[n] = rrelu(rdegI[n]·Σ_{s∈in(n)} Zs[s])
// gemm_y:   Ys = rdegO ⊙ (H1@W2m)
// gather64_mlp: out[n] = relu(rdegI[n]·Σ Ys[s] + b1)@w2 + b2

#define HM1 127

static constexpr float RRELU_SLOPE = (1.0f / 8.0f + 1.0f / 3.0f) * 0.5f;

__device__ __forceinline__ float sigmoidf_(float x) {
    return 1.0f / (1.0f + expf(-x));
}

// ---------------------------------------------------------------------------
// phase1: blocks [0,nbE): degree histogram; [nbE,nbE+512): gate transpose
//   AT[cell][0][k][i]=W0+U0 (z), [1]=W1+U1 (r), [2]=W2, [3]=U2
// ---------------------------------------------------------------------------
__global__ __launch_bounds__(256) void phase1(
    const int* __restrict__ src, const int* __restrict__ dst,
    int* __restrict__ degO, int* __restrict__ degI, int E, int nbE,
    const float* __restrict__ g1W, const float* __restrict__ g1U,
    const float* __restrict__ g2W, const float* __restrict__ g2U,
    float* __restrict__ AT)
{
    int bid = blockIdx.x;
    if (bid < nbE) {
        int e = bid * 256 + threadIdx.x;
        if (e < E) {
            atomicAdd(&degO[src[e]], 1);
            atomicAdd(&degI[dst[e]], 1);
        }
    } else {
        int t = (bid - nbE) * 256 + threadIdx.x;   // < 8*16384
        int m = t >> 14;          // matrix 0..7
        int k = (t >> 7) & 127;   // row of AT
        int i = t & 127;          // col of AT
        const float* W = (m < 4) ? g1W : g2W;
        const float* U = (m < 4) ? g1U : g2U;
        int which = m & 3;
        float v;
        if (which == 0)      v = W[i * 128 + k] + U[i * 128 + k];
        else if (which == 1) v = W[16384 + i * 128 + k] + U[16384 + i * 128 + k];
        else if (which == 2) v = W[32768 + i * 128 + k];
        else                 v = U[32768 + i * 128 + k];
        AT[t] = v;
    }
}

// ---------------------------------------------------------------------------
// phase2: blocks [0,128): gru (2 columns per block, 8 steps);
//         block 128: scan degI -> row_ptr; blocks [129,129+nbN): rdeg
// ---------------------------------------------------------------------------
__global__ __launch_bounds__(256) void phase2(
    const float* __restrict__ W1_0, const float* __restrict__ W2_0,
    const float* __restrict__ AT,
    const float* __restrict__ g1b, const float* __restrict__ g2b,
    float* __restrict__ W1f, float* __restrict__ W2f,
    const int* __restrict__ degO, const int* __restrict__ degI,
    float* __restrict__ rdegO, float* __restrict__ rdegI,
    int* __restrict__ row_ptr, int N)
{
    __shared__ float smem[512];   // gru: w[2][128]+rw[2][128]; scan: int[256]
    int bid = blockIdx.x;
    if (bid < 128) {
        const int half = threadIdx.x >> 7;
        const int i = threadIdx.x & 127;
        int c = bid * 2 + half;               // 0..255
        if (c > 254) c = 254;                 // dup col 254; same-value write
        const int cell = (c >= 128) ? 1 : 0;
        const int cc = cell ? (c - 128) : c;  // cell2: 0..126

        const float* A  = AT + cell * 4 * 16384;
        const float* A0 = A;
        const float* A1 = A + 16384;
        const float* B0 = A + 32768;
        const float* B1 = A + 49152;
        const float* gb = cell ? g2b : g1b;
        const int   ldb = cell ? HM1 : 128;
        const float* W0 = cell ? W2_0 : W1_0;
        const int   ldw = cell ? HM1 : 128;

        float* w  = smem + half * 128;
        float* rw = smem + 256 + half * 128;

        const float zb = gb[i * ldb + cc];
        const float rb = gb[128 * ldb + i * ldb + cc];
        const float hb = gb[2 * 128 * ldb + i * ldb + cc];
        float wi = W0[i * ldw + cc];
        w[i] = wi;
        __syncthreads();

        for (int s = 0; s < 8; ++s) {
            float zacc = zb, racc = rb, tacc = hb;
            #pragma unroll 4
            for (int k = 0; k < 128; ++k) {
                float wk = w[k];
                zacc += A0[k * 128 + i] * wk;
                racc += A1[k * 128 + i] * wk;
                tacc += B0[k * 128 + i] * wk;
            }
            float r = sigmoidf_(racc);
            rw[i] = r * wi;
            __syncthreads();
            #pragma unroll 4
            for (int k = 0; k < 128; ++k)
                tacc += B1[k * 128 + i] * rw[k];
            float z = sigmoidf_(zacc);
            float t = tanhf(tacc);
            float nwi = (1.0f - z) * wi + z * t;
            __syncthreads();      // loop1+loop2 reads done before overwrite
            wi = nwi;
            w[i] = nwi;
            __syncthreads();
        }
        float* Wf = cell ? W2f : W1f;
        Wf[i * 128 + cc] = wi;    // ld=128 (W2f padded)
    } else if (bid == 128) {
        int* sums = (int*)smem;
        const int t = threadIdx.x;
        const int chunk = (N + 255) / 256;
        const int lo = t * chunk;
        const int hi = min(lo + chunk, N);
        int s = 0;
        for (int i2 = lo; i2 < hi; ++i2) s += degI[i2];
        sums[t] = s;
        __syncthreads();
        for (int off = 1; off < 256; off <<= 1) {
            int v = (t >= off) ? sums[t - off] : 0;
            __syncthreads();
            sums[t] += v;
            __syncthreads();
        }
        int base = (t > 0) ? sums[t - 1] : 0;
        for (int i2 = lo; i2 < hi; ++i2) {
            row_ptr[i2] = base;
            base += degI[i2];
        }
        if (t == 255) row_ptr[N] = sums[255];
    } else {
        int n = (bid - 129) * 256 + threadIdx.x;
        if (n < N) {
            rdegO[n] = rsqrtf(fmaxf((float)degO[n], 1.0f));
            rdegI[n] = rsqrtf(fmaxf((float)degI[n], 1.0f));
        }
    }
}

// ---------------------------------------------------------------------------
// phase3: blocks [0,nbE): build_csr; [nbE,nbE+2*nbN): gemm_z; last 32: W2m.
// gemm_z: Zs[row,:] = rdegO[row] * (x7[row,:] @ W1f), 64-col half per block.
// ---------------------------------------------------------------------------
__global__ __launch_bounds__(256) void phase3(
    const int* __restrict__ src, const int* __restrict__ dst,
    const int* __restrict__ row_ptr, int* __restrict__ cursor,
    int* __restrict__ srcs, int E, int nbE,
    const float* __restrict__ x7, const float* __restrict__ W1f,
    const float* __restrict__ rdegO, float* __restrict__ Zs, int N, int nbN,
    const float* __restrict__ W2f, const float* __restrict__ mw1,
    float* __restrict__ W2m)
{
    int bid = blockIdx.x;
    if (bid < nbE) {
        int e = bid * 256 + threadIdx.x;
        if (e < E) {
            int d = dst[e];
            int pos = row_ptr[d] + atomicAdd(&cursor[d], 1);
            srcs[pos] = src[e];
        }
    } else if (bid < nbE + 2 * nbN) {
        int b = bid - nbE;
        int half = b & 1;
        int row = (b >> 1) * 256 + threadIdx.x;
        int c0 = half * 64;
        if (row >= N) return;

        float acc[64];
        #pragma unroll
        for (int j = 0; j < 64; ++j) acc[j] = 0.0f;

        const float4* xr = reinterpret_cast<const float4*>(x7 + (size_t)row * 128);
        for (int k4 = 0; k4 < 32; ++k4) {
            float4 xv = xr[k4];
            const float* wr = W1f + (k4 * 4) * 128 + c0;
            #pragma unroll
            for (int j = 0; j < 64; ++j) acc[j] += xv.x * wr[j];
            wr += 128;
            #pragma unroll
            for (int j = 0; j < 64; ++j) acc[j] += xv.y * wr[j];
            wr += 128;
            #pragma unroll
            for (int j = 0; j < 64; ++j) acc[j] += xv.z * wr[j];
            wr += 128;
            #pragma unroll
            for (int j = 0; j < 64; ++j) acc[j] += xv.w * wr[j];
        }

        float ro = rdegO[row];
        float* zr = Zs + (size_t)row * 128 + c0;
        #pragma unroll
        for (int j = 0; j < 64; j += 4) {
            float4 v;
            v.x = acc[j] * ro; v.y = acc[j + 1] * ro;
            v.z = acc[j + 2] * ro; v.w = acc[j + 3] * ro;
            *reinterpret_cast<float4*>(zr + j) = v;
        }
    } else {
        int idx = (bid - nbE - 2 * nbN) * 256 + threadIdx.x;  // < 8192
        int i = idx >> 6, j = idx & 63;
        float acc = 0.0f;
        for (int k = 0; k < HM1; ++k)
            acc += W2f[i * 128 + k] * mw1[k * 64 + j];
        W2m[idx] = acc;
    }
}

// ---------------------------------------------------------------------------
// H1[n,:] = rrelu(rdegI[n] * sum_{s in in(n)} Zs[s,:])   (weight-free)
// One wave per node; lane owns 2 cols; 8 independent row loads in flight.
// ---------------------------------------------------------------------------
__global__ __launch_bounds__(256) void gather128(
    const float* __restrict__ Zs, const int* __restrict__ srcs,
    const int* __restrict__ row_ptr, const float* __restrict__ rdegI,
    float* __restrict__ H1, int N)
{
    int n = (blockIdx.x * 256 + threadIdx.x) >> 6;
    int lane = threadIdx.x & 63;
    if (n >= N) return;
    int lo = row_ptr[n], hi = row_ptr[n + 1];
    float ax = 0.0f, ay = 0.0f;
    for (int base = lo; base < hi; base += 64) {
        int cnt = min(hi - base, 64);
        int idx = (lane < cnt) ? srcs[base + lane] : 0;
        int j = 0;
        for (; j + 8 <= cnt; j += 8) {
            int s0 = __shfl(idx, j + 0), s1 = __shfl(idx, j + 1);
            int s2 = __shfl(idx, j + 2), s3 = __shfl(idx, j + 3);
            int s4 = __shfl(idx, j + 4), s5 = __shfl(idx, j + 5);
            int s6 = __shfl(idx, j + 6), s7 = __shfl(idx, j + 7);
            float2 v0 = *reinterpret_cast<const float2*>(Zs + (size_t)s0 * 128 + lane * 2);
            float2 v1 = *reinterpret_cast<const float2*>(Zs + (size_t)s1 * 128 + lane * 2);
            float2 v2 = *reinterpret_cast<const float2*>(Zs + (size_t)s2 * 128 + lane * 2);
            float2 v3 = *reinterpret_cast<const float2*>(Zs + (size_t)s3 * 128 + lane * 2);
            float2 v4 = *reinterpret_cast<const float2*>(Zs + (size_t)s4 * 128 + lane * 2);
            float2 v5 = *reinterpret_cast<const float2*>(Zs + (size_t)s5 * 128 + lane * 2);
            float2 v6 = *reinterpret_cast<const float2*>(Zs + (size_t)s6 * 128 + lane * 2);
            float2 v7 = *reinterpret_cast<const float2*>(Zs + (size_t)s7 * 128 + lane * 2);
            ax += v0.x + v1.x + v2.x + v3.x + v4.x + v5.x + v6.x + v7.x;
            ay += v0.y + v1.y + v2.y + v3.y + v4.y + v5.y + v6.y + v7.y;
        }
        for (; j < cnt; ++j) {
            int s0 = __shfl(idx, j);
            float2 v0 = *reinterpret_cast<const float2*>(Zs + (size_t)s0 * 128 + lane * 2);
            ax += v0.x;
            ay += v0.y;
        }
    }
    float ri = rdegI[n];
    ax *= ri; ay *= ri;
    ax = ax >= 0.0f ? ax : RRELU_SLOPE * ax;
    ay = ay >= 0.0f ? ay : RRELU_SLOPE * ay;
    float2 o; o.x = ax; o.y = ay;
    *reinterpret_cast<float2*>(H1 + (size_t)n * 128 + lane * 2) = o;
}

// Ys = diag(rdegO) * (H1 @ W2m) : [N,128] @ [128,64]
__global__ __launch_bounds__(256) void gemm_y(
    const float* __restrict__ H1, const float* __restrict__ W2m,
    const float* __restrict__ rdegO, float* __restrict__ Ys, int N)
{
    int row = blockIdx.x * 256 + threadIdx.x;
    if (row >= N) return;

    float acc[64];
    #pragma unroll
    for (int j = 0; j < 64; ++j) acc[j] = 0.0f;

    const float4* hr = reinterpret_cast<const float4*>(H1 + (size_t)row * 128);
    for (int k4 = 0; k4 < 32; ++k4) {
        float4 h = hr[k4];
        const float* wr = W2m + (k4 * 4) * 64;
        #pragma unroll
        for (int j = 0; j < 64; ++j) acc[j] += h.x * wr[j];
        wr += 64;
        #pragma unroll
        for (int j = 0; j < 64; ++j) acc[j] += h.y * wr[j];
        wr += 64;
        #pragma unroll
        for (int j = 0; j < 64; ++j) acc[j] += h.z * wr[j];
        wr += 64;
        #pragma unroll
        for (int j = 0; j < 64; ++j) acc[j] += h.w * wr[j];
    }

    float ro = rdegO[row];
    float* yr = Ys + (size_t)row * 64;
    #pragma unroll
    for (int j = 0; j < 64; j += 4) {
        float4 v;
        v.x = acc[j] * ro; v.y = acc[j + 1] * ro;
        v.z = acc[j + 2] * ro; v.w = acc[j + 3] * ro;
        *reinterpret_cast<float4*>(yr + j) = v;
    }
}

// out[n,:] = relu(rdegI[n]*sum Ys[s,:] + b1) @ w2 + b2  (wave reduction)
__global__ __launch_bounds__(256) void gather64_mlp(
    const float* __restrict__ Ys, const int* __restrict__ srcs,
    const int* __restrict__ row_ptr, const float* __restrict__ rdegI,
    const float* __restrict__ b1, const float* __restrict__ w2,
    const float* __restrict__ b2, float* __restrict__ out, int N)
{
    int n = (blockIdx.x * 256 + threadIdx.x) >> 6;
    int lane = threadIdx.x & 63;
    if (n >= N) return;
    int lo = row_ptr[n], hi = row_ptr[n + 1];
    float acc = 0.0f;
    for (int base = lo; base < hi; base += 64) {
        int cnt = min(hi - base, 64);
        int idx = (lane < cnt) ? srcs[base + lane] : 0;
        int j = 0;
        for (; j + 8 <= cnt; j += 8) {
            int s0 = __shfl(idx, j + 0), s1 = __shfl(idx, j + 1);
            int s2 = __shfl(idx, j + 2), s3 = __shfl(idx, j + 3);
            int s4 = __shfl(idx, j + 4), s5 = __shfl(idx, j + 5);
            int s6 = __shfl(idx, j + 6), s7 = __shfl(idx, j + 7);
            acc += Ys[(size_t)s0 * 64 + lane] + Ys[(size_t)s1 * 64 + lane]
                 + Ys[(size_t)s2 * 64 + lane] + Ys[(size_t)s3 * 64 + lane]
                 + Ys[(size_t)s4 * 64 + lane] + Ys[(size_t)s5 * 64 + lane]
                 + Ys[(size_t)s6 * 64 + lane] + Ys[(size_t)s7 * 64 + lane];
        }
        for (; j < cnt; ++j) {
            int s0 = __shfl(idx, j);
            acc += Ys[(size_t)s0 * 64 + lane];
        }
    }
    float z = acc * rdegI[n];
    float t = fmaxf(z + b1[lane], 0.0f);
    float p0 = t * w2[lane * 2 + 0];
    float p1 = t * w2[lane * 2 + 1];
    #pragma unroll
    for (int off = 32; off; off >>= 1) {
        p0 += __shfl_xor(p0, off);
        p1 += __shfl_xor(p1, off);
    }
    if (lane == 0) {
        out[(size_t)n * 2 + 0] = p0 + b2[0];
        out[(size_t)n * 2 + 1] = p1 + b2[1];
    }
}

extern "C" void kernel_launch(void* const* d_in, const int* in_sizes, int n_in,
                              void* d_out, int out_size, void* d_ws, size_t ws_size,
                              hipStream_t stream) {
    const float* feats = (const float*)d_in[0];
    const int*   src   = (const int*)d_in[1];
    const int*   dst   = (const int*)d_in[2];
    const float* W1_0  = (const float*)d_in[3];
    const float* W2_0  = (const float*)d_in[4];
    const float* g1W   = (const float*)d_in[5];
    const float* g1U   = (const float*)d_in[6];
    const float* g1b   = (const float*)d_in[7];
    const float* g2W   = (const float*)d_in[8];
    const float* g2U   = (const float*)d_in[9];
    const float* g2b   = (const float*)d_in[10];
    const float* mw1   = (const float*)d_in[11];
    const float* mb1   = (const float*)d_in[12];
    const float* mw2   = (const float*)d_in[13];
    const float* mb2   = (const float*)d_in[14];
    float* out = (float*)d_out;

    const int E = in_sizes[1];
    const int N = in_sizes[0] / (8 * 128);
    const int nbE = (E + 255) / 256;
    const int nbN = (N + 255) / 256;

    // workspace layout
    float* ws    = (float*)d_ws;
    float* W1f   = ws;                        // 16384
    float* W2f   = W1f + 16384;               // 16384
    float* W2m   = W2f + 16384;               // 8192
    float* AT    = W2m + 8192;                // 8*16384
    float* rdegO = AT + 8 * 16384;            // N
    float* rdegI = rdegO + N;                 // N
    int*   degO  = (int*)(rdegI + N);         // N  ┐
    int*   degI  = degO + N;                  // N  ├ contiguous, one memset
    int*   cursor= degI + N;                  // N  ┘
    int*   row_ptr = cursor + N;              // N+1
    int*   srcs  = row_ptr + N + 1;           // E
    float* Zs    = (float*)(srcs + E);        // N*128
    float* H1    = Zs + (size_t)N * 128;      // N*128
    float* Ys    = Zs;                        // N*64 aliases Zs (dead by then)

    const float* x7 = feats + (size_t)7 * N * 128;

    hipMemsetAsync(degO, 0, sizeof(int) * 3 * (size_t)N, stream);

    phase1<<<nbE + 512, 256, 0, stream>>>(src, dst, degO, degI, E, nbE,
                                          g1W, g1U, g2W, g2U, AT);

    phase2<<<129 + nbN, 256, 0, stream>>>(W1_0, W2_0, AT, g1b, g2b, W1f, W2f,
                                          degO, degI, rdegO, rdegI, row_ptr, N);

    phase3<<<nbE + 2 * nbN + 32, 256, 0, stream>>>(
        src, dst, row_ptr, cursor, srcs, E, nbE,
        x7, W1f, rdegO, Zs, N, nbN, W2f, mw1, W2m);

    int ngather = ((N * 64) + 255) / 256;     // 4 nodes (waves) per block
    gather128<<<ngather, 256, 0, stream>>>(Zs, srcs, row_ptr, rdegI, H1, N);

    gemm_y<<<nbN, 256, 0, stream>>>(H1, W2m, rdegO, Ys, N);

    gather64_mlp<<<ngather, 256, 0, stream>>>(Ys, srcs, row_ptr, rdegI,
                                              mb1, mw2, mb2, out, N);
}